// Round 11
// baseline (203.901 us; speedup 1.0000x reference)
//
#include <hip/hip_runtime.h>

// ForwardSumLossWithBlank: CTC forward (alpha) loss, blank=0, targets=arange(text_len).
// B=32, T=2000 mel frames, C=400 classes. Output: scalar mean loss (fp32).
//
// FAST path (needs ~66 MB of d_ws):
//   Pass A (k_prob): masked NORMALIZED probs -> bf16 [T][512] in ws, permuted for the
//          2-wave split layout (wave w, lane l gets dwords (pair,pair+2),(pair+1,pair+3),
//          pair base = w*256+l*4). `ls` holds p0[t] f32.
//   Pass B (k_ctc_fast): TWO waves per sample, state-split at pair 256. Wave1 trails
//          wave0 by 16 steps; wave0 streams its boundary odd-state through a 32-slot
//          LDS ring; 8-step phases with 2 barriers; renorm on the JOINT max (shared
//          exact-pow2 frame, integer exacc); boundary values converted across frames
//          by the product of the last 2-3 scales (int exponents, clamped).
//          Per wave per step: 1 global_load_dwordx2, 4 bf16 converts (pipelined one
//          step ahead), 8 packed VOP3P ops, 1 DPP, 1 LDS write (w0) / 1 fma inject (w1).
//   Pass C (k_final): deterministic mean.
// FALLBACK path (small ws): proven R4 kernels (raw exp(logits), -lsum epilogue).

static constexpr int B_ = 32;
static constexpr int T_ = 2000;
static constexpr int C_ = 400;
static constexpr float M0f    = 1e20f;
static constexpr float LOGM0f = 46.05170186f;   // ln(1e20) (fallback path)

typedef float f32x2 __attribute__((ext_vector_type(2)));

template <int CTRL>
__device__ __forceinline__ float dppmov(float v) {
    // mov_dpp, bound_ctrl=1: invalid-source lanes read 0 (safe: alphas >= 0).
    return __int_as_float(__builtin_amdgcn_update_dpp(
        0, __float_as_int(v), CTRL, 0xF, 0xF, true));
}

__device__ __forceinline__ float bcast0(float v) {
    return __int_as_float(__builtin_amdgcn_readfirstlane(__float_as_int(v)));
}

__device__ __forceinline__ unsigned bf16rne(float f) {
    unsigned u = __float_as_uint(f);
    u += 0x7FFFu + ((u >> 16) & 1u);
    return u >> 16;
}

__device__ __forceinline__ float pow2i(int e) {      // exact 2^e, e in [-126, 127]
    return __int_as_float((unsigned)(127 + e) << 23);
}

// ---------------- Pass A: masked normalized probs (bf16, padded 512, split-permuted) ----------------
// fast mode (pbf!=null): ls[row] = p0 (f32 normalized blank prob)
// fallback   (pbf==null): ls[row] = ln(sum exp)
__global__ __launch_bounds__(256) void k_prob(const float* __restrict__ logits,
                                              const int* __restrict__ text_lens,
                                              unsigned short* __restrict__ pbf,
                                              float* __restrict__ ls) {
    const int lane = threadIdx.x & 63;
    const int row  = blockIdx.x * 4 + (threadIdx.x >> 6);   // grid = B*T/4 exactly
    const int b    = row / T_;
    const int tl   = text_lens[b];
    const float* __restrict__ r = logits + (size_t)row * C_;

    const int c0 = lane * 8;
    float v[8];
    if (c0 < C_) {           // row is 1600 B, 16B-aligned; lane<50 reads [c0, c0+8)
        const float4 a = *(const float4*)(r + c0);
        const float4 c = *(const float4*)(r + c0 + 4);
        v[0]=a.x; v[1]=a.y; v[2]=a.z; v[3]=a.w; v[4]=c.x; v[5]=c.y; v[6]=c.z; v[7]=c.w;
    } else {
#pragma unroll
        for (int e = 0; e < 8; ++e) v[e] = 0.f;             // masked below anyway
    }
    float ex[8]; float s = 0.f;
#pragma unroll
    for (int e = 0; e < 8; ++e) {
        const int c = c0 + e;
        const float t = (c < tl) ? __expf(v[e]) : 0.f;      // tl <= 400 -> cols>=400 masked
        ex[e] = t; s += t;
    }
#pragma unroll
    for (int off = 32; off; off >>= 1) s += __shfl_xor(s, off);

    if (pbf) {
        const float inv = 1.0f / s;
        // split-permuted: dword j of the uint4 = halfword pair for target lane 2ll+(j>>1),
        // slot j&1: (col c0+4(j>>1)+(j&1), col c0+4(j>>1)+(j&1)+2)
        uint4 st;
        st.x = bf16rne(ex[0]*inv) | (bf16rne(ex[2]*inv) << 16);
        st.y = bf16rne(ex[1]*inv) | (bf16rne(ex[3]*inv) << 16);
        st.z = bf16rne(ex[4]*inv) | (bf16rne(ex[6]*inv) << 16);
        st.w = bf16rne(ex[5]*inv) | (bf16rne(ex[7]*inv) << 16);
        *(uint4*)(pbf + (size_t)row * 512 + c0) = st;       // coalesced 1 KB/wave
        if (lane == 0) ls[row] = ex[0] * inv;               // p0 (col 0 always < tl)
    } else {
        if (lane == 0) ls[row] = __logf(s);
    }
}

// ---------------- Pass A2 (fallback only): per-sample sum of ln-denominators ----------------
__global__ __launch_bounds__(256) void k_lsum(const float* __restrict__ ls,
                                              const int* __restrict__ mel_lens,
                                              float* __restrict__ lsums) {
    const int b  = blockIdx.x;
    const int ml = mel_lens[b];
    float s = 0.f;
    for (int i = threadIdx.x; i < ml; i += 256) s += ls[(size_t)b * T_ + i];
#pragma unroll
    for (int off = 32; off; off >>= 1) s += __shfl_xor(s, off);
    __shared__ float ws[4];
    if ((threadIdx.x & 63) == 0) ws[threadIdx.x >> 6] = s;
    __syncthreads();
    if (threadIdx.x == 0) lsums[b] = (ws[0] + ws[1]) + (ws[2] + ws[3]);
}

// ---------------- scalar recursion pieces (fallback path, proven R4) ----------------
template <int PP>
__device__ __forceinline__ void step_update(const float p0, const float* __restrict__ p,
                                            float* __restrict__ aeven, float* __restrict__ aodd) {
    float prev = dppmov<0x138>(aodd[PP - 1]);
#pragma unroll
    for (int j = 0; j < PP; ++j) {
        const float oldodd = aodd[j];
        const float e = aeven[j] + prev;
        aeven[j] = e * p0;
        aodd[j]  = (oldodd + e) * p[j];
        prev = oldodd;
    }
}

template <int PP>
__device__ __forceinline__ void renorm(float* __restrict__ aeven, float* __restrict__ aodd,
                                       float& lognorm) {
    float m = 0.f;
#pragma unroll
    for (int j = 0; j < PP; ++j) m = fmaxf(m, fmaxf(aeven[j], aodd[j]));
    m = fmaxf(m, dppmov<0x111>(m));
    m = fmaxf(m, dppmov<0x112>(m));
    m = fmaxf(m, dppmov<0x114>(m));
    m = fmaxf(m, dppmov<0x118>(m));
    m = fmaxf(m, dppmov<0x142>(m));
    m = fmaxf(m, dppmov<0x143>(m));
    const float wm  = __int_as_float(__builtin_amdgcn_readlane(__float_as_int(m), 63));
    const float inv = 1.0f / wm;
    lognorm += __logf(wm) - LOGM0f;
#pragma unroll
    for (int j = 0; j < PP; ++j) {
        aeven[j] = (aeven[j] * inv) * M0f;
        aodd[j]  = (aodd[j]  * inv) * M0f;
    }
}

// ---------------- Pass B (fast): 2-wave state-split, packed-FP32 recursion ----------------
// Wave w owns pairs [256w, 256w+256): lane l holds slot0=(q0,q0+2), slot1=(q0+1,q0+3),
// q0 = 256w+4l. prev(slot0) = (dpp(Ao[1].y) [+ cross-wave inject], Ao[1].x);
// prev(slot1) = Ao[0]. Wave1 trails wave0 by 16 steps.
__global__ __launch_bounds__(128) void k_ctc_fast(const unsigned short* __restrict__ pbf,
                                                  const int* __restrict__ text_lens,
                                                  const int* __restrict__ mel_lens,
                                                  const float* __restrict__ p0arr,
                                                  float* __restrict__ losses) {
    __shared__ float BND[2][32][64];   // boundary ring: [wave][step&31][lane] (w1 region = dump)
    __shared__ float MX[2];            // per-wave max exchange
    __shared__ float CB[2];            // contrib partials
    const int b    = blockIdx.x;
    const int tid  = threadIdx.x;
    const int w    = tid >> 6;
    const int lane = tid & 63;
    const int tl   = text_lens[b];
    const int ml   = mel_lens[b];
    const uint2* __restrict__ base = (const uint2*)(pbf + (size_t)b * T_ * 512);
    const float* __restrict__ p0b  = p0arr + (size_t)b * T_;
    const int off = (w << 6) + lane;           // uint2 offset within a row (stride 128)
    float* __restrict__ BNDW = &BND[w][0][0];
    const float* __restrict__ BR = &BND[0][0][0];

    for (int i = tid; i < 2 * 32 * 64; i += 128) (&BND[0][0][0])[i] = 0.f;
    __syncthreads();

    // 16-deep rotating register ring; prologue loads rows 1..16 (ml >= 1024).
    uint2 raw[16];
#pragma unroll
    for (int s = 0; s < 16; ++s) raw[s] = base[(size_t)(s + 1) * 128 + off];

    f32x2 Ae[2], Ao[2];
    Ae[0] = Ae[1] = Ao[0] = Ao[1] = (f32x2){0.f, 0.f};
    if (tid == 0) {                             // pair 0 = wave0 lane0 slot0.x
        const float p00 = p0b[0] * 0x1p66f;
        Ae[0].x = p00; Ao[0].x = p00;
    }
    int exacc = -66, eh1 = 0, eh2 = 0;          // shared frame: exponent history
    const float mask0 = (tid == 64) ? 1.f : 0.f;  // wave1 lane0 gets the cross-wave inject

    f32x2 pA0, pA1, pB0, pB1;
    pB0 = pB1 = (f32x2){0.f, 0.f};
    {   // CVT row 1 (slot 0) into pA
        const uint2 wv = raw[0];
        pA0.x = __uint_as_float(wv.x << 16); pA0.y = __uint_as_float(wv.x & 0xFFFF0000u);
        pA1.x = __uint_as_float(wv.y << 16); pA1.y = __uint_as_float(wv.y & 0xFFFF0000u);
    }
    float p0A = p0b[1], p0B = p0b[2];
    float bnds[8];
#pragma unroll
    for (int i = 0; i < 8; ++i) bnds[i] = 0.f;

    const int Pst = (ml - 17) >> 3;             // last unclamped phase
    const int TP  = (ml + 22) >> 3;             // total phases (wave1 finishes at 8TP-16)
    int pc = 1, tw = 0, tw31 = 0;

    // one step: consume row t (p converted last step), reload slot, CVT next, update
#define STEP2(S, PH8, PIN0, PIN1, P0IN, POUT0, POUT1, PRED)                        \
    { const int t = tw + (S);                                                      \
      if (!(PRED) || ((unsigned)(t - 1) < (unsigned)(ml - 1))) {                   \
        { int tr = t + 16; if (PRED) { if (tr > ml - 1) tr = ml - 1; }             \
          raw[((PH8) + (S)) & 15] = base[(size_t)tr * 128 + off]; }                \
        { const uint2 wv = raw[((PH8) + (S) + 1) & 15];                            \
          POUT0.x = __uint_as_float(wv.x << 16);                                   \
          POUT0.y = __uint_as_float(wv.x & 0xFFFF0000u);                           \
          POUT1.x = __uint_as_float(wv.y << 16);                                   \
          POUT1.y = __uint_as_float(wv.y & 0xFFFF0000u); }                         \
        { float bnd = dppmov<0x138>(Ao[1].y);                                      \
          bnd = fmaf(bnds[S], mask0, bnd);                                         \
          f32x2 prev0; prev0.x = bnd; prev0.y = Ao[1].x;                           \
          const f32x2 E0 = Ae[0] + prev0;                                          \
          const f32x2 E1 = Ae[1] + Ao[0];                                          \
          const f32x2 T0 = Ao[0] + E0;                                             \
          const f32x2 T1 = Ao[1] + E1;                                             \
          const f32x2 vp0 = {P0IN, P0IN};                                          \
          Ae[0] = E0 * vp0; Ae[1] = E1 * vp0;                                      \
          Ao[0] = T0 * PIN0; Ao[1] = T1 * PIN1; }                                  \
        { int t2 = t + 2; if (PRED) { if (t2 > ml - 1) t2 = ml - 1; }              \
          P0IN = p0b[t2]; }                                                        \
        BNDW[(((tw31 + (S)) & 31) << 6) + lane] = Ao[1].y;                         \
      } }

    // 8 steps + joint renorm + boundary prefetch for the next phase
#define PHASE2(PH8, PRED)                                                          \
    { STEP2(0, PH8, pA0, pA1, p0A, pB0, pB1, PRED)                                 \
      STEP2(1, PH8, pB0, pB1, p0B, pA0, pA1, PRED)                                 \
      STEP2(2, PH8, pA0, pA1, p0A, pB0, pB1, PRED)                                 \
      STEP2(3, PH8, pB0, pB1, p0B, pA0, pA1, PRED)                                 \
      STEP2(4, PH8, pA0, pA1, p0A, pB0, pB1, PRED)                                 \
      STEP2(5, PH8, pB0, pB1, p0B, pA0, pA1, PRED)                                 \
      STEP2(6, PH8, pA0, pA1, p0A, pB0, pB1, PRED)                                 \
      STEP2(7, PH8, pB0, pB1, p0B, pA0, pA1, PRED)                                 \
      f32x2 m2 = __builtin_elementwise_max(__builtin_elementwise_max(Ae[0], Ao[0]),\
                                           __builtin_elementwise_max(Ae[1], Ao[1]));\
      float m = fmaxf(m2.x, m2.y);                                                 \
      m = fmaxf(m, dppmov<0x111>(m));                                              \
      m = fmaxf(m, dppmov<0x112>(m));                                              \
      m = fmaxf(m, dppmov<0x114>(m));                                              \
      m = fmaxf(m, dppmov<0x118>(m));                                              \
      m = fmaxf(m, dppmov<0x142>(m));                                              \
      m = fmaxf(m, dppmov<0x143>(m));                                              \
      const float wm = __int_as_float(__builtin_amdgcn_readlane(__float_as_int(m), 63)); \
      MX[w] = wm;                                                                  \
      __syncthreads();                                                             \
      const float joint = fmaxf(wm, MX[w ^ 1]);                                    \
      int ex = ((__float_as_int(joint) >> 23) & 0xFF) - 127;                       \
      if (ex < -60) ex = -60;                                                      \
      exacc += ex - 66;                                                            \
      const int enew = 66 - ex;                                                    \
      const float sc = pow2i(enew);                                                \
      const f32x2 scv = {sc, sc};                                                  \
      Ae[0] *= scv; Ae[1] *= scv; Ao[0] *= scv; Ao[1] *= scv;                      \
      int fa = eh2 + eh1 + enew; if (fa > 100) fa = 100; if (fa < -126) fa = -126; \
      int fb = eh1 + enew;       if (fb > 100) fb = 100; if (fb < -126) fb = -126; \
      eh2 = eh1; eh1 = enew;                                                       \
      const float fav = pow2i(fa), fbv = pow2i(fb);                                \
      { const int u31 = (8 * pc - 16) & 31;                                        \
        _Pragma("unroll")                                                          \
        for (int i = 0; i < 8; ++i) bnds[i] = BR[(((u31 + i) & 31) << 6) + 63]; }  \
      bnds[0] *= fav;                                                              \
      _Pragma("unroll")                                                            \
      for (int i = 1; i < 8; ++i) bnds[i] *= fbv;                                  \
      __syncthreads(); }

#define RUNPHASE(PRED)                                                             \
    { tw = 8 * pc - 7 - 16 * w; tw31 = tw & 31;                                    \
      if ((pc - 1) & 1) { PHASE2(8, PRED) } else { PHASE2(0, PRED) }               \
      ++pc; }

    RUNPHASE(true)                       // pc=1: wave0 t=1..8,  wave1 idle
    RUNPHASE(true)                       // pc=2: wave0 t=9..16, wave1 idle
    for (; pc <= Pst; ) RUNPHASE(false)  // steady: no clamps, no step guards
    for (; pc <= TP;  ) RUNPHASE(true)   // tail: per-step guards + clamps
#undef RUNPHASE
#undef PHASE2
#undef STEP2

    // epilogue: probs normalized -> ll = ln(contrib) + exacc*ln2 (shared exacc)
    float contrib = 0.f;
    {
        const int q0 = w * 256 + lane * 4;
        if (q0     == tl)     contrib += Ae[0].x;
        if (q0     == tl - 1) contrib += Ao[0].x;
        if (q0 + 2 == tl)     contrib += Ae[0].y;
        if (q0 + 2 == tl - 1) contrib += Ao[0].y;
        if (q0 + 1 == tl)     contrib += Ae[1].x;
        if (q0 + 1 == tl - 1) contrib += Ao[1].x;
        if (q0 + 3 == tl)     contrib += Ae[1].y;
        if (q0 + 3 == tl - 1) contrib += Ao[1].y;
    }
#pragma unroll
    for (int o = 32; o; o >>= 1) contrib += __shfl_xor(contrib, o);
    CB[w] = contrib;
    __syncthreads();
    if (tid == 0) {
        const float c = CB[0] + CB[1];
        float loss = 0.f;
        if (c > 0.f) {
            const float ll = __logf(c) + (float)exacc * 0.69314718056f;
            loss = -ll / (float)tl;
        }
        losses[b] = loss;
    }
}

// ---------------- Pass B (fallback, proven R4): direct logit loads ----------------
template <int PP>
__device__ __forceinline__ void ctc_run_slow(const float* __restrict__ Lb, float lsum,
                                             int tl, int ml, float* __restrict__ loss_out) {
    const int lane = threadIdx.x;
    const int base = lane * PP;
    int   idx[PP];
    float mask[PP];
#pragma unroll
    for (int j = 0; j < PP; ++j) {
        const int k = base + j;
        idx[j]  = (k < C_) ? k : (C_ - 1);
        mask[j] = (k < tl) ? 1.f : 0.f;
    }
    float raw[8][PP];
#pragma unroll
    for (int s = 0; s < 8; ++s) {
        const float* __restrict__ rowp = Lb + (size_t)(s + 1) * C_;
#pragma unroll
        for (int j = 0; j < PP; ++j) raw[s][j] = rowp[idx[j]];
    }
    float aeven[PP], aodd[PP];
#pragma unroll
    for (int j = 0; j < PP; ++j) { aeven[j] = 0.f; aodd[j] = 0.f; }
    {
        const float a00 = __expf(Lb[0]) * M0f;
        if (lane == 0) { aeven[0] = a00; aodd[0] = a00; }
    }
    float lognorm = -LOGM0f;
    int tb = 1;
    for (; tb + 8 <= ml; tb += 8) {
#pragma unroll
        for (int s = 0; s < 8; ++s) {
            const int tt = tb + s;
            const float p0 = __expf(bcast0(raw[s][0]));
            float p[PP];
#pragma unroll
            for (int j = 0; j < PP; ++j) p[j] = __expf(raw[s][j]) * mask[j];
            { int tr = tt + 8; if (tr > ml - 1) tr = ml - 1;
              const float* __restrict__ rowp = Lb + (size_t)tr * C_;
#pragma unroll
              for (int j = 0; j < PP; ++j) raw[s][j] = rowp[idx[j]]; }
            step_update<PP>(p0, p, aeven, aodd);
            if (s == 7) renorm<PP>(aeven, aodd, lognorm);
        }
    }
#pragma unroll
    for (int s = 0; s < 8; ++s) {
        const int tt = tb + s;
        if (tt < ml) {
            const float p0 = __expf(bcast0(raw[s][0]));
            float p[PP];
#pragma unroll
            for (int j = 0; j < PP; ++j) p[j] = __expf(raw[s][j]) * mask[j];
            step_update<PP>(p0, p, aeven, aodd);
            if (s == 7) renorm<PP>(aeven, aodd, lognorm);
        }
    }
    float contrib = 0.f;
#pragma unroll
    for (int j = 0; j < PP; ++j) {
        const int k = base + j;
        if (k == tl)     contrib += aeven[j];
        if (k == tl - 1) contrib += aodd[j];
    }
#pragma unroll
    for (int off = 32; off; off >>= 1) contrib += __shfl_xor(contrib, off);
    if (lane == 0) {
        float loss = 0.f;
        if (contrib > 0.f) {
            const float ll = __logf(contrib) + lognorm - lsum;   // raw domain: -lsum needed
            loss = -ll / (float)tl;
        }
        *loss_out = loss;
    }
}

__global__ __launch_bounds__(64) void k_ctc_slow(const float* __restrict__ logits,
                                                 const int* __restrict__ text_lens,
                                                 const int* __restrict__ mel_lens,
                                                 const float* __restrict__ lsums,
                                                 float* __restrict__ losses) {
    const int b  = blockIdx.x;
    const int tl = text_lens[b];
    const int ml = mel_lens[b];
    const float lsum = lsums[b];
    const float* Lb = logits + (size_t)b * T_ * C_;
    float* lo = losses + b;
    const int PP = (tl + 1 + 63) >> 6;
    switch (PP) {
        case 1: ctc_run_slow<1>(Lb, lsum, tl, ml, lo); break;
        case 2: ctc_run_slow<2>(Lb, lsum, tl, ml, lo); break;
        case 3: ctc_run_slow<3>(Lb, lsum, tl, ml, lo); break;
        case 4: ctc_run_slow<4>(Lb, lsum, tl, ml, lo); break;
        case 5: ctc_run_slow<5>(Lb, lsum, tl, ml, lo); break;
        case 6: ctc_run_slow<6>(Lb, lsum, tl, ml, lo); break;
        default: ctc_run_slow<7>(Lb, lsum, tl, ml, lo); break;
    }
}

// ---------------- Pass C: deterministic mean ----------------
__global__ __launch_bounds__(64) void k_final(const float* __restrict__ losses,
                                              float* __restrict__ out) {
    const int lane = threadIdx.x;
    float v = (lane < B_) ? losses[lane] : 0.f;
#pragma unroll
    for (int off = 32; off; off >>= 1) v += __shfl_xor(v, off);
    if (lane == 0) out[0] = v * (1.0f / B_);
}

extern "C" void kernel_launch(void* const* d_in, const int* in_sizes, int n_in,
                              void* d_out, int out_size, void* d_ws, size_t ws_size,
                              hipStream_t stream) {
    const float* logits    = (const float*)d_in[0];   // [B,1,T,C] fp32
    const int*   text_lens = (const int*)d_in[1];     // [B] int32
    const int*   mel_lens  = (const int*)d_in[2];     // [B] int32
    float* out = (float*)d_out;

    const size_t PBF_BYTES = (size_t)B_ * T_ * 512 * 2;           // 65,536,000
    const size_t need = PBF_BYTES + (size_t)B_ * T_ * 4 + 2 * B_ * 4 + 64;

    if (ws_size >= need) {
        unsigned short* pbf = (unsigned short*)d_ws;
        float* ls     = (float*)((char*)d_ws + PBF_BYTES);   // holds p0[t] in fast mode
        float* lsums  = ls + (size_t)B_ * T_;
        float* losses = lsums + B_;
        k_prob<<<B_ * T_ / 4, 256, 0, stream>>>(logits, text_lens, pbf, ls);
        k_ctc_fast<<<B_, 128, 0, stream>>>(pbf, text_lens, mel_lens, ls, losses);
        k_final<<<1, 64, 0, stream>>>(losses, out);
    } else {
        float* ls     = (float*)d_ws;
        float* lsums  = ls + (size_t)B_ * T_;
        float* losses = lsums + B_;
        k_prob<<<B_ * T_ / 4, 256, 0, stream>>>(logits, text_lens, nullptr, ls);
        k_lsum<<<B_, 256, 0, stream>>>(ls, mel_lens, lsums);
        k_ctc_slow<<<B_, 64, 0, stream>>>(logits, text_lens, mel_lens, lsums, losses);
        k_final<<<1, 64, 0, stream>>>(losses, out);
    }
}